// Round 18
// baseline (259.507 us; speedup 1.0000x reference)
//
#include <hip/hip_runtime.h>
#include <cmath>

#define TABLE_NUM 16
#define T_SIZE    4096
#define Z_DIM     512
#define IMG       256
#define D_TAB     (TABLE_NUM * T_SIZE * 2)       // 131072
#define BATCH     8
#define HID       64
#define N_PIX     (IMG * IMG)                    // 65536
#define PRIME_Y   2654435761u
#define KCHUNK    4
#define KLEN      (Z_DIM / KCHUNK)               // 128
#define NG4       (D_TAB / 4)                    // 32768 float4 col-groups
#define REPS      6                              // measurement repeat factor

typedef _Float16 v8h  __attribute__((ext_vector_type(8)));
typedef _Float16 v2h  __attribute__((ext_vector_type(2)));
typedef float    v4f  __attribute__((ext_vector_type(4)));

struct ResArr { float r[TABLE_NUM]; };

// ---------------------------------------------------------------------------
// MEASUREMENT ROUND: R17 source, hash_mlp body repeated 6x (idempotent,
// per-wave mbuf -> no cross-rep barriers) to surface it above the ~155 us
// poison-fill cutoff in rocprof top-5. Per-rep dur = dispatch_dur / 6.
// ---------------------------------------------------------------------------

__global__ void prep_weights(const float* __restrict__ w1, const float* __restrict__ w2,
                             const float* __restrict__ w3, const float* __restrict__ z,
                             _Float16* __restrict__ w1T, _Float16* __restrict__ w2T,
                             _Float16* __restrict__ w3T, float* __restrict__ zT)
{
    const int t0  = blockIdx.x * 256 + threadIdx.x;
    const int stp = gridDim.x * 256;
    for (int i = t0; i < HID * 32; i += stp) {
        int n = i >> 5, k = i & 31;
        w1T[i] = (_Float16)w1[k * HID + n];
    }
    for (int i = t0; i < HID * HID; i += stp) {
        int n = i >> 6, k = i & 63;
        w2T[i] = (_Float16)w2[k * HID + n];
    }
    for (int i = t0; i < 16 * HID; i += stp) {
        int n = i >> 6, k = i & 63;
        w3T[i] = (_Float16)(n < 3 ? w3[k * 3 + n] : 0.f);
    }
    for (int i = t0; i < Z_DIM * BATCH; i += stp) {
        int k = i >> 3, b = i & 7;
        zT[i] = z[b * Z_DIM + k];
    }
}

__global__ __launch_bounds__(256) void gen_partial(
    const float* __restrict__ zT, const float* __restrict__ w,
    float* __restrict__ part)
{
    const int c  = blockIdx.x >> 7;
    const int g  = (blockIdx.x & 127) * 256 + threadIdx.x;
    const int k0 = c * KLEN;
    const float4* wp = reinterpret_cast<const float4*>(w) + g;

    float4 acc[BATCH];
#pragma unroll
    for (int b = 0; b < BATCH; ++b) acc[b] = make_float4(0.f, 0.f, 0.f, 0.f);

#pragma unroll 8
    for (int kk = 0; kk < KLEN; ++kk) {
        const int k = k0 + kk;
        float4 wv = wp[(size_t)k * NG4];
        const float* zr = zT + k * BATCH;
#pragma unroll
        for (int b = 0; b < BATCH; ++b) {
            float zv = zr[b];
            acc[b].x = fmaf(zv, wv.x, acc[b].x);
            acc[b].y = fmaf(zv, wv.y, acc[b].y);
            acc[b].z = fmaf(zv, wv.z, acc[b].z);
            acc[b].w = fmaf(zv, wv.w, acc[b].w);
        }
    }

    float4* pp = reinterpret_cast<float4*>(part);
#pragma unroll
    for (int b = 0; b < BATCH; ++b)
        pp[((size_t)(c * BATCH + b) << 15) + g] = acc[b];
}

__global__ __launch_bounds__(256) void gen_reduce(
    const float* __restrict__ part, const float* __restrict__ bt,
    float* __restrict__ tabs)
{
    const int i = blockIdx.x * 256 + threadIdx.x;
    const int b = i >> 15, g = i & (NG4 - 1);
    const float4* pp = reinterpret_cast<const float4*>(part);

    float4 s = pp[((size_t)b << 15) + g];
#pragma unroll
    for (int c = 1; c < KCHUNK; ++c) {
        float4 p = pp[((size_t)(c * BATCH + b) << 15) + g];
        s.x += p.x; s.y += p.y; s.z += p.z; s.w += p.w;
    }
    float4 bv = reinterpret_cast<const float4*>(bt)[g];
    s.x += bv.x; s.y += bv.y; s.z += bv.z; s.w += bv.w;
    reinterpret_cast<float4*>(tabs)[((size_t)b << 15) + g] = s;
}

__global__ __launch_bounds__(256) void hash_mlp(
    const float* __restrict__ tabs,
    const _Float16* __restrict__ w1T, const _Float16* __restrict__ w2T,
    const _Float16* __restrict__ w3T,
    const float* __restrict__ b1, const float* __restrict__ b2,
    const float* __restrict__ b3,
    float* __restrict__ out, ResArr res)
{
    __shared__ _Float16 mbuf[4][64][72];
    const int tid  = threadIdx.x;
    const int wid  = tid >> 6;
    const int lane = tid & 63;
    const int b    = blockIdx.x & 7;
    const int tile = blockIdx.x >> 3;
    const int i0   = (tile >> 4) * 16 + wid * 4;
    const int j0   = (tile & 15) * 16;

    const int arow = lane & 15;
    const int kgrp = lane >> 4;

    const float2* tb2 = reinterpret_cast<const float2*>(tabs + (size_t)b * D_TAB);
    const float cyp = ((float)(j0 + arow) + 0.5f) * (1.0f / IMG);

#pragma unroll 1
    for (int rep = 0; rep < REPS; ++rep) {

        // ---- features straight into a1 fragments ----
        v8h a1[4];
#pragma unroll
        for (int q = 0; q < 4; ++q) {
            const float r = (kgrp == 0) ? res.r[q]
                          : (kgrp == 1) ? res.r[4 + q]
                          : (kgrp == 2) ? res.r[8 + q]
                          :               res.r[12 + q];
            const float2* tl = tb2 + (kgrp * 4 + q) * T_SIZE;
            float py = cyp * r;
            float fy0 = floorf(py);
            float fy = py - fy0;
            unsigned y0 = (unsigned)(int)fy0;
            unsigned hy0 = y0 * PRIME_Y, hy1 = (y0 + 1u) * PRIME_Y;
#pragma unroll
            for (int mt = 0; mt < 4; ++mt) {
                const float cxp = ((float)(i0 + mt) + 0.5f) * (1.0f / IMG);
                float px = cxp * r;
                float fx0 = floorf(px);
                float fx = px - fx0;
                unsigned x0 = (unsigned)(int)fx0;
                unsigned i00 = (x0 ^ hy0) & (T_SIZE - 1);
                unsigned i10 = ((x0 + 1u) ^ hy0) & (T_SIZE - 1);
                unsigned i01 = (x0 ^ hy1) & (T_SIZE - 1);
                unsigned i11 = ((x0 + 1u) ^ hy1) & (T_SIZE - 1);
                float2 f00 = tl[i00], f10 = tl[i10], f01 = tl[i01], f11 = tl[i11];
                float w00 = (1.f - fx) * (1.f - fy);
                float w10 = fx * (1.f - fy);
                float w01 = (1.f - fx) * fy;
                float w11 = fx * fy;
                float e0 = f00.x * w00 + f10.x * w10 + f01.x * w01 + f11.x * w11;
                float e1 = f00.y * w00 + f10.y * w10 + f01.y * w01 + f11.y * w11;
                a1[mt][2 * q]     = (_Float16)e0;
                a1[mt][2 * q + 1] = (_Float16)e1;
            }
        }

        // ---- layer 1 ----
#pragma unroll
        for (int nt = 0; nt < 4; ++nt) {
            v8h bf1 = *reinterpret_cast<const v8h*>(&w1T[(nt * 16 + arow) * 32 + kgrp * 8]);
            const float bias = b1[nt * 16 + arow];
#pragma unroll
            for (int mt = 0; mt < 4; ++mt) {
                v4f c = {0.f, 0.f, 0.f, 0.f};
                c = __builtin_amdgcn_mfma_f32_16x16x32_f16(a1[mt], bf1, c, 0, 0, 0);
#pragma unroll
                for (int e = 0; e < 4; ++e)
                    mbuf[wid][mt * 16 + kgrp * 4 + e][nt * 16 + arow] =
                        (_Float16)fmaxf(c[e] + bias, 0.f);
            }
        }

        // ---- layer 2 ----
        v8h a2[4][2];
#pragma unroll
        for (int mt = 0; mt < 4; ++mt) {
            a2[mt][0] = *reinterpret_cast<const v8h*>(&mbuf[wid][mt * 16 + arow][kgrp * 8]);
            a2[mt][1] = *reinterpret_cast<const v8h*>(&mbuf[wid][mt * 16 + arow][32 + kgrp * 8]);
        }
#pragma unroll
        for (int nt = 0; nt < 4; ++nt) {
            v8h bf2a = *reinterpret_cast<const v8h*>(&w2T[(nt * 16 + arow) * 64 + kgrp * 8]);
            v8h bf2b = *reinterpret_cast<const v8h*>(&w2T[(nt * 16 + arow) * 64 + 32 + kgrp * 8]);
            const float bias = b2[nt * 16 + arow];
#pragma unroll
            for (int mt = 0; mt < 4; ++mt) {
                v4f c = {0.f, 0.f, 0.f, 0.f};
                c = __builtin_amdgcn_mfma_f32_16x16x32_f16(a2[mt][0], bf2a, c, 0, 0, 0);
                c = __builtin_amdgcn_mfma_f32_16x16x32_f16(a2[mt][1], bf2b, c, 0, 0, 0);
#pragma unroll
                for (int e = 0; e < 4; ++e)
                    mbuf[wid][mt * 16 + kgrp * 4 + e][nt * 16 + arow] =
                        (_Float16)fmaxf(c[e] + bias, 0.f);
            }
        }

        // ---- layer 3 ----
        const float bias3 = (arow < 3) ? b3[arow] : 0.f;
#pragma unroll
        for (int mt = 0; mt < 4; ++mt) {
            v8h bf3a = *reinterpret_cast<const v8h*>(&w3T[arow * 64 + kgrp * 8]);
            v8h bf3b = *reinterpret_cast<const v8h*>(&w3T[arow * 64 + 32 + kgrp * 8]);
            v8h a0  = *reinterpret_cast<const v8h*>(&mbuf[wid][mt * 16 + arow][kgrp * 8]);
            v8h a1v = *reinterpret_cast<const v8h*>(&mbuf[wid][mt * 16 + arow][32 + kgrp * 8]);
            v4f c = {0.f, 0.f, 0.f, 0.f};
            c = __builtin_amdgcn_mfma_f32_16x16x32_f16(a0,  bf3a, c, 0, 0, 0);
            c = __builtin_amdgcn_mfma_f32_16x16x32_f16(a1v, bf3b, c, 0, 0, 0);
            if (arow < 3) {
                float4 st;
                st.x = tanhf(c[0] + bias3);
                st.y = tanhf(c[1] + bias3);
                st.z = tanhf(c[2] + bias3);
                st.w = tanhf(c[3] + bias3);
                size_t idx = ((size_t)b * 3 + arow) * N_PIX
                           + (size_t)(i0 + mt) * IMG + j0 + kgrp * 4;
                *reinterpret_cast<float4*>(&out[idx]) = st;
            }
        }
    }
}

extern "C" void kernel_launch(void* const* d_in, const int* in_sizes, int n_in,
                              void* d_out, int out_size, void* d_ws, size_t ws_size,
                              hipStream_t stream)
{
    const float* z  = (const float*)d_in[0];
    const float* wt = (const float*)d_in[1];
    const float* bt = (const float*)d_in[2];
    const float* w1 = (const float*)d_in[3];
    const float* b1 = (const float*)d_in[4];
    const float* w2 = (const float*)d_in[5];
    const float* b2 = (const float*)d_in[6];
    const float* w3 = (const float*)d_in[7];
    const float* b3 = (const float*)d_in[8];
    float* out  = (float*)d_out;

    char* ws = (char*)d_ws;
    float*     tabs = (float*)ws;                            // 4 MB
    float*     part = (float*)(ws + (4 << 20));              // 16 MB partials
    _Float16*  w1T  = (_Float16*)(ws + (20 << 20));          // 4 KB
    _Float16*  w2T  = (_Float16*)(ws + (20 << 20) + 4096);   // 8 KB
    _Float16*  w3T  = (_Float16*)(ws + (20 << 20) + 12288);  // 2 KB
    float*     zT   = (float*)(ws + (20 << 20) + 16384);     // 16 KB

    ResArr ra;
    const double growth = std::exp((std::log(256.0) - std::log(16.0)) / 15.0);
    for (int l = 0; l < TABLE_NUM; ++l)
        ra.r[l] = (float)(16.0 * std::pow(growth, (double)l));

    prep_weights<<<16, 256, 0, stream>>>(w1, w2, w3, z, w1T, w2T, w3T, zT);
    gen_partial<<<KCHUNK * (NG4 / 256), 256, 0, stream>>>(zT, wt, part);
    gen_reduce<<<BATCH * NG4 / 256, 256, 0, stream>>>(part, bt, tabs);
    hash_mlp<<<BATCH * (N_PIX / 256), 256, 0, stream>>>(
        tabs, w1T, w2T, w3T, b1, b2, b3, out, ra);
}

// Round 19
// 99.700 us; speedup vs baseline: 2.6029x; 2.6029x over previous
//
#include <hip/hip_runtime.h>
#include <cmath>

#define TABLE_NUM 16
#define T_SIZE    4096
#define Z_DIM     512
#define IMG       256
#define D_TAB     (TABLE_NUM * T_SIZE * 2)       // 131072
#define BATCH     8
#define HID       64
#define N_PIX     (IMG * IMG)                    // 65536
#define PRIME_Y   2654435761u
#define KCHUNK    4
#define KLEN      (Z_DIM / KCHUNK)               // 128
#define NG4       (D_TAB / 4)                    // 32768 float4 col-groups

typedef _Float16 v8h  __attribute__((ext_vector_type(8)));
typedef _Float16 v2h  __attribute__((ext_vector_type(2)));
typedef float    v4f  __attribute__((ext_vector_type(4)));

struct ResArr { float r[TABLE_NUM]; };

// ---------------------------------------------------------------------------
// Kernel 0: weight transpose/cast + z transpose — grid-stride, 16 blocks.
// ---------------------------------------------------------------------------
__global__ void prep_weights(const float* __restrict__ w1, const float* __restrict__ w2,
                             const float* __restrict__ w3, const float* __restrict__ z,
                             _Float16* __restrict__ w1T, _Float16* __restrict__ w2T,
                             _Float16* __restrict__ w3T, float* __restrict__ zT)
{
    const int t0  = blockIdx.x * 256 + threadIdx.x;
    const int stp = gridDim.x * 256;
    for (int i = t0; i < HID * 32; i += stp) {
        int n = i >> 5, k = i & 31;
        w1T[i] = (_Float16)w1[k * HID + n];
    }
    for (int i = t0; i < HID * HID; i += stp) {
        int n = i >> 6, k = i & 63;
        w2T[i] = (_Float16)w2[k * HID + n];
    }
    for (int i = t0; i < 16 * HID; i += stp) {
        int n = i >> 6, k = i & 63;
        w3T[i] = (_Float16)(n < 3 ? w3[k * 3 + n] : 0.f);
    }
    for (int i = t0; i < Z_DIM * BATCH; i += stp) {
        int k = i >> 3, b = i & 7;
        zT[i] = z[b * Z_DIM + k];
    }
}

// ---------------------------------------------------------------------------
// Kernel 1a: k-split partial GEMM (unchanged from R7; ~44 us @ 6.4 TB/s).
// ---------------------------------------------------------------------------
__global__ __launch_bounds__(256) void gen_partial(
    const float* __restrict__ zT, const float* __restrict__ w,
    float* __restrict__ part)
{
    const int c  = blockIdx.x >> 7;
    const int g  = (blockIdx.x & 127) * 256 + threadIdx.x;
    const int k0 = c * KLEN;
    const float4* wp = reinterpret_cast<const float4*>(w) + g;

    float4 acc[BATCH];
#pragma unroll
    for (int b = 0; b < BATCH; ++b) acc[b] = make_float4(0.f, 0.f, 0.f, 0.f);

#pragma unroll 8
    for (int kk = 0; kk < KLEN; ++kk) {
        const int k = k0 + kk;
        float4 wv = wp[(size_t)k * NG4];
        const float* zr = zT + k * BATCH;
#pragma unroll
        for (int b = 0; b < BATCH; ++b) {
            float zv = zr[b];
            acc[b].x = fmaf(zv, wv.x, acc[b].x);
            acc[b].y = fmaf(zv, wv.y, acc[b].y);
            acc[b].z = fmaf(zv, wv.z, acc[b].z);
            acc[b].w = fmaf(zv, wv.w, acc[b].w);
        }
    }

    float4* pp = reinterpret_cast<float4*>(part);
#pragma unroll
    for (int b = 0; b < BATCH; ++b)
        pp[((size_t)(c * BATCH + b) << 15) + g] = acc[b];
}

// ---------------------------------------------------------------------------
// Kernel 1b: fold partials + bias (unchanged from R7; ~3.5 us).
// ---------------------------------------------------------------------------
__global__ __launch_bounds__(256) void gen_reduce(
    const float* __restrict__ part, const float* __restrict__ bt,
    float* __restrict__ tabs)
{
    const int i = blockIdx.x * 256 + threadIdx.x;
    const int b = i >> 15, g = i & (NG4 - 1);
    const float4* pp = reinterpret_cast<const float4*>(part);

    float4 s = pp[((size_t)b << 15) + g];
#pragma unroll
    for (int c = 1; c < KCHUNK; ++c) {
        float4 p = pp[((size_t)(c * BATCH + b) << 15) + g];
        s.x += p.x; s.y += p.y; s.z += p.z; s.w += p.w;
    }
    float4 bv = reinterpret_cast<const float4*>(bt)[g];
    s.x += bv.x; s.y += bv.y; s.z += bv.z; s.w += bv.w;
    reinterpret_cast<float4*>(tabs)[((size_t)b << 15) + g] = s;
}

// ---------------------------------------------------------------------------
// Kernel 2: R17 base + TWO-TILE interleave per wave (R18 counters: VALUBusy
// 46%, MfmaUtil 8%, latency-bound serial chain). Both tiles' 64-gather sets
// issue before either MLP runs -> tile1's global latency hides under tile0's
// bilerp+MFMA phase. mbuf reused across tiles (same-wave in-order DS).
// Per-pixel arithmetic bit-identical to R17. Grid halves to 1024 blocks.
// NO min-waves launch_bounds (convicted R11/R14).
// ---------------------------------------------------------------------------
__global__ __launch_bounds__(256) void hash_mlp(
    const float* __restrict__ tabs,
    const _Float16* __restrict__ w1T, const _Float16* __restrict__ w2T,
    const _Float16* __restrict__ w3T,
    const float* __restrict__ b1, const float* __restrict__ b2,
    const float* __restrict__ b3,
    float* __restrict__ out, ResArr res)
{
    __shared__ _Float16 mbuf[4][64][72];
    const int tid  = threadIdx.x;
    const int wid  = tid >> 6;
    const int lane = tid & 63;
    const int b    = blockIdx.x & 7;          // batch == XCD (round-robin)
    const int pair = blockIdx.x >> 3;         // two consecutive 16x16 tiles

    const int arow = lane & 15;        // A row / B col / C col
    const int kgrp = lane >> 4;        // k-group

    const float2* tb2 = reinterpret_cast<const float2*>(tabs + (size_t)b * D_TAB);

    // ---- feature phase for BOTH tiles: fragments straight into registers --
    v8h a1t[2][4];
    int i0t[2], j0t[2];
#pragma unroll
    for (int tt = 0; tt < 2; ++tt) {
        const int tile = pair * 2 + tt;
        const int i0   = (tile >> 4) * 16 + wid * 4;
        const int j0   = (tile & 15) * 16;
        i0t[tt] = i0; j0t[tt] = j0;
        const float cyp = ((float)(j0 + arow) + 0.5f) * (1.0f / IMG);
#pragma unroll
        for (int q = 0; q < 4; ++q) {
            const float r = (kgrp == 0) ? res.r[q]
                          : (kgrp == 1) ? res.r[4 + q]
                          : (kgrp == 2) ? res.r[8 + q]
                          :               res.r[12 + q];
            const float2* tl = tb2 + (kgrp * 4 + q) * T_SIZE;
            float py = cyp * r;
            float fy0 = floorf(py);
            float fy = py - fy0;
            unsigned y0 = (unsigned)(int)fy0;
            unsigned hy0 = y0 * PRIME_Y, hy1 = (y0 + 1u) * PRIME_Y;
#pragma unroll
            for (int mt = 0; mt < 4; ++mt) {
                const float cxp = ((float)(i0 + mt) + 0.5f) * (1.0f / IMG);
                float px = cxp * r;
                float fx0 = floorf(px);
                float fx = px - fx0;
                unsigned x0 = (unsigned)(int)fx0;
                unsigned i00 = (x0 ^ hy0) & (T_SIZE - 1);
                unsigned i10 = ((x0 + 1u) ^ hy0) & (T_SIZE - 1);
                unsigned i01 = (x0 ^ hy1) & (T_SIZE - 1);
                unsigned i11 = ((x0 + 1u) ^ hy1) & (T_SIZE - 1);
                float2 f00 = tl[i00], f10 = tl[i10], f01 = tl[i01], f11 = tl[i11];
                float w00 = (1.f - fx) * (1.f - fy);
                float w10 = fx * (1.f - fy);
                float w01 = (1.f - fx) * fy;
                float w11 = fx * fy;
                float e0 = f00.x * w00 + f10.x * w10 + f01.x * w01 + f11.x * w11;
                float e1 = f00.y * w00 + f10.y * w10 + f01.y * w01 + f11.y * w11;
                a1t[tt][mt][2 * q]     = (_Float16)e0;
                a1t[tt][mt][2 * q + 1] = (_Float16)e1;
            }
        }
    }

    // ---- MLP for each tile (mbuf reused; same-wave in-order DS) ----
#pragma unroll
    for (int tt = 0; tt < 2; ++tt) {
        const int i0 = i0t[tt], j0 = j0t[tt];

        // layer 1: 32 -> 64; per-nt fused relu+write
#pragma unroll
        for (int nt = 0; nt < 4; ++nt) {
            v8h bf1 = *reinterpret_cast<const v8h*>(&w1T[(nt * 16 + arow) * 32 + kgrp * 8]);
            const float bias = b1[nt * 16 + arow];
#pragma unroll
            for (int mt = 0; mt < 4; ++mt) {
                v4f c = {0.f, 0.f, 0.f, 0.f};
                c = __builtin_amdgcn_mfma_f32_16x16x32_f16(a1t[tt][mt], bf1, c, 0, 0, 0);
#pragma unroll
                for (int e = 0; e < 4; ++e)
                    mbuf[wid][mt * 16 + kgrp * 4 + e][nt * 16 + arow] =
                        (_Float16)fmaxf(c[e] + bias, 0.f);
            }
        }

        // layer 2: 64 -> 64; a2 fully in regs first (WAR-safe)
        v8h a2[4][2];
#pragma unroll
        for (int mt = 0; mt < 4; ++mt) {
            a2[mt][0] = *reinterpret_cast<const v8h*>(&mbuf[wid][mt * 16 + arow][kgrp * 8]);
            a2[mt][1] = *reinterpret_cast<const v8h*>(&mbuf[wid][mt * 16 + arow][32 + kgrp * 8]);
        }
#pragma unroll
        for (int nt = 0; nt < 4; ++nt) {
            v8h bf2a = *reinterpret_cast<const v8h*>(&w2T[(nt * 16 + arow) * 64 + kgrp * 8]);
            v8h bf2b = *reinterpret_cast<const v8h*>(&w2T[(nt * 16 + arow) * 64 + 32 + kgrp * 8]);
            const float bias = b2[nt * 16 + arow];
#pragma unroll
            for (int mt = 0; mt < 4; ++mt) {
                v4f c = {0.f, 0.f, 0.f, 0.f};
                c = __builtin_amdgcn_mfma_f32_16x16x32_f16(a2[mt][0], bf2a, c, 0, 0, 0);
                c = __builtin_amdgcn_mfma_f32_16x16x32_f16(a2[mt][1], bf2b, c, 0, 0, 0);
#pragma unroll
                for (int e = 0; e < 4; ++e)
                    mbuf[wid][mt * 16 + kgrp * 4 + e][nt * 16 + arow] =
                        (_Float16)fmaxf(c[e] + bias, 0.f);
            }
        }

        // layer 3: 64 -> 3 (padded 16), tanh, coalesced row stores
        const float bias3 = (arow < 3) ? b3[arow] : 0.f;
#pragma unroll
        for (int mt = 0; mt < 4; ++mt) {
            v8h bf3a = *reinterpret_cast<const v8h*>(&w3T[arow * 64 + kgrp * 8]);
            v8h bf3b = *reinterpret_cast<const v8h*>(&w3T[arow * 64 + 32 + kgrp * 8]);
            v8h a0  = *reinterpret_cast<const v8h*>(&mbuf[wid][mt * 16 + arow][kgrp * 8]);
            v8h a1v = *reinterpret_cast<const v8h*>(&mbuf[wid][mt * 16 + arow][32 + kgrp * 8]);
            v4f c = {0.f, 0.f, 0.f, 0.f};
            c = __builtin_amdgcn_mfma_f32_16x16x32_f16(a0,  bf3a, c, 0, 0, 0);
            c = __builtin_amdgcn_mfma_f32_16x16x32_f16(a1v, bf3b, c, 0, 0, 0);
            if (arow < 3) {
                float4 st;
                st.x = tanhf(c[0] + bias3);
                st.y = tanhf(c[1] + bias3);
                st.z = tanhf(c[2] + bias3);
                st.w = tanhf(c[3] + bias3);
                size_t idx = ((size_t)b * 3 + arow) * N_PIX
                           + (size_t)(i0 + mt) * IMG + j0 + kgrp * 4;
                *reinterpret_cast<float4*>(&out[idx]) = st;
            }
        }
    }
}

extern "C" void kernel_launch(void* const* d_in, const int* in_sizes, int n_in,
                              void* d_out, int out_size, void* d_ws, size_t ws_size,
                              hipStream_t stream)
{
    const float* z  = (const float*)d_in[0];
    const float* wt = (const float*)d_in[1];
    const float* bt = (const float*)d_in[2];
    const float* w1 = (const float*)d_in[3];
    const float* b1 = (const float*)d_in[4];
    const float* w2 = (const float*)d_in[5];
    const float* b2 = (const float*)d_in[6];
    const float* w3 = (const float*)d_in[7];
    const float* b3 = (const float*)d_in[8];
    float* out  = (float*)d_out;

    char* ws = (char*)d_ws;
    float*     tabs = (float*)ws;                            // 4 MB
    float*     part = (float*)(ws + (4 << 20));              // 16 MB partials
    _Float16*  w1T  = (_Float16*)(ws + (20 << 20));          // 4 KB
    _Float16*  w2T  = (_Float16*)(ws + (20 << 20) + 4096);   // 8 KB
    _Float16*  w3T  = (_Float16*)(ws + (20 << 20) + 12288);  // 2 KB
    float*     zT   = (float*)(ws + (20 << 20) + 16384);     // 16 KB

    ResArr ra;
    const double growth = std::exp((std::log(256.0) - std::log(16.0)) / 15.0);
    for (int l = 0; l < TABLE_NUM; ++l)
        ra.r[l] = (float)(16.0 * std::pow(growth, (double)l));

    prep_weights<<<16, 256, 0, stream>>>(w1, w2, w3, z, w1T, w2T, w3T, zT);
    gen_partial<<<KCHUNK * (NG4 / 256), 256, 0, stream>>>(zT, wt, part);
    gen_reduce<<<BATCH * NG4 / 256, 256, 0, stream>>>(part, bt, tabs);
    // two tiles per block: 8 batches x 128 tile-pairs = 1024 blocks
    hash_mlp<<<BATCH * (N_PIX / 512), 256, 0, stream>>>(
        tabs, w1T, w2T, w3T, b1, b2, b3, out, ra);
}

// Round 20
// 90.924 us; speedup vs baseline: 2.8541x; 1.0965x over previous
//
#include <hip/hip_runtime.h>
#include <cmath>

#define TABLE_NUM 16
#define T_SIZE    4096
#define Z_DIM     512
#define IMG       256
#define D_TAB     (TABLE_NUM * T_SIZE * 2)       // 131072
#define BATCH     8
#define HID       64
#define N_PIX     (IMG * IMG)                    // 65536
#define PRIME_Y   2654435761u
#define KCHUNK    4
#define KLEN      (Z_DIM / KCHUNK)               // 128
#define NG4       (D_TAB / 4)                    // 32768 float4 col-groups

typedef _Float16 v8h  __attribute__((ext_vector_type(8)));
typedef _Float16 v2h  __attribute__((ext_vector_type(2)));
typedef float    v4f  __attribute__((ext_vector_type(4)));

struct ResArr { float r[TABLE_NUM]; };

// ---------------------------------------------------------------------------
// Kernel 0: weight transpose/cast + z transpose — grid-stride, 16 blocks.
// ---------------------------------------------------------------------------
__global__ void prep_weights(const float* __restrict__ w1, const float* __restrict__ w2,
                             const float* __restrict__ w3, const float* __restrict__ z,
                             _Float16* __restrict__ w1T, _Float16* __restrict__ w2T,
                             _Float16* __restrict__ w3T, float* __restrict__ zT)
{
    const int t0  = blockIdx.x * 256 + threadIdx.x;
    const int stp = gridDim.x * 256;
    for (int i = t0; i < HID * 32; i += stp) {
        int n = i >> 5, k = i & 31;
        w1T[i] = (_Float16)w1[k * HID + n];
    }
    for (int i = t0; i < HID * HID; i += stp) {
        int n = i >> 6, k = i & 63;
        w2T[i] = (_Float16)w2[k * HID + n];
    }
    for (int i = t0; i < 16 * HID; i += stp) {
        int n = i >> 6, k = i & 63;
        w3T[i] = (_Float16)(n < 3 ? w3[k * 3 + n] : 0.f);
    }
    for (int i = t0; i < Z_DIM * BATCH; i += stp) {
        int k = i >> 3, b = i & 7;
        zT[i] = z[b * Z_DIM + k];
    }
}

// ---------------------------------------------------------------------------
// Kernel 1a: k-split partial GEMM (unchanged from R7; ~44 us @ 6.4 TB/s).
// ---------------------------------------------------------------------------
__global__ __launch_bounds__(256) void gen_partial(
    const float* __restrict__ zT, const float* __restrict__ w,
    float* __restrict__ part)
{
    const int c  = blockIdx.x >> 7;
    const int g  = (blockIdx.x & 127) * 256 + threadIdx.x;
    const int k0 = c * KLEN;
    const float4* wp = reinterpret_cast<const float4*>(w) + g;

    float4 acc[BATCH];
#pragma unroll
    for (int b = 0; b < BATCH; ++b) acc[b] = make_float4(0.f, 0.f, 0.f, 0.f);

#pragma unroll 8
    for (int kk = 0; kk < KLEN; ++kk) {
        const int k = k0 + kk;
        float4 wv = wp[(size_t)k * NG4];
        const float* zr = zT + k * BATCH;
#pragma unroll
        for (int b = 0; b < BATCH; ++b) {
            float zv = zr[b];
            acc[b].x = fmaf(zv, wv.x, acc[b].x);
            acc[b].y = fmaf(zv, wv.y, acc[b].y);
            acc[b].z = fmaf(zv, wv.z, acc[b].z);
            acc[b].w = fmaf(zv, wv.w, acc[b].w);
        }
    }

    float4* pp = reinterpret_cast<float4*>(part);
#pragma unroll
    for (int b = 0; b < BATCH; ++b)
        pp[((size_t)(c * BATCH + b) << 15) + g] = acc[b];
}

// ---------------------------------------------------------------------------
// Kernel 1b: fold partials + bias (unchanged from R7; ~3.5 us).
// ---------------------------------------------------------------------------
__global__ __launch_bounds__(256) void gen_reduce(
    const float* __restrict__ part, const float* __restrict__ bt,
    float* __restrict__ tabs)
{
    const int i = blockIdx.x * 256 + threadIdx.x;
    const int b = i >> 15, g = i & (NG4 - 1);
    const float4* pp = reinterpret_cast<const float4*>(part);

    float4 s = pp[((size_t)b << 15) + g];
#pragma unroll
    for (int c = 1; c < KCHUNK; ++c) {
        float4 p = pp[((size_t)(c * BATCH + b) << 15) + g];
        s.x += p.x; s.y += p.y; s.z += p.z; s.w += p.w;
    }
    float4 bv = reinterpret_cast<const float4*>(bt)[g];
    s.x += bv.x; s.y += bv.y; s.z += bv.z; s.w += bv.w;
    reinterpret_cast<float4*>(tabs)[((size_t)b << 15) + g] = s;
}

// ---------------------------------------------------------------------------
// Kernel 2: R17 base (90.8 us) with the feature phase restructured into two
// explicit load-batches: each half issues ALL 32 corner loads (2 levels x
// 4 pixels x 4 corners) into named registers BEFORE any bilerp consumes
// them. Exposed gather-latency windows drop ~4-5 -> 2 per tile (R18
// counters: 20 us of the 38 is stall; VGPR was 100 = compiler buffering
// only ~8 loads). All arithmetic bit-identical to R17. One tile per block
// (R19's two-tile interleave regressed). NO min-waves launch_bounds.
// ---------------------------------------------------------------------------
__global__ __launch_bounds__(256) void hash_mlp(
    const float* __restrict__ tabs,
    const _Float16* __restrict__ w1T, const _Float16* __restrict__ w2T,
    const _Float16* __restrict__ w3T,
    const float* __restrict__ b1, const float* __restrict__ b2,
    const float* __restrict__ b3,
    float* __restrict__ out, ResArr res)
{
    __shared__ _Float16 mbuf[4][64][72];
    const int tid  = threadIdx.x;
    const int wid  = tid >> 6;
    const int lane = tid & 63;
    const int b    = blockIdx.x & 7;          // batch == XCD (round-robin)
    const int tile = blockIdx.x >> 3;         // 16x16 pixel block
    const int i0   = (tile >> 4) * 16 + wid * 4;
    const int j0   = (tile & 15) * 16;

    const int arow = lane & 15;        // A row / B col / C col
    const int kgrp = lane >> 4;        // k-group

    const float2* tb2 = reinterpret_cast<const float2*>(tabs + (size_t)b * D_TAB);
    const float cyp = ((float)(j0 + arow) + 0.5f) * (1.0f / IMG);

    // ---- features: two 32-load batches, then bilerp (bit-identical math) --
    v8h a1[4];
#pragma unroll
    for (int h = 0; h < 2; ++h) {
        float2 fA[4][4], fB[4][4];
        float  fxA[4], fxB[4], fyA, fyB;

        {   // level q = 2h
            const int q = 2 * h;
            const float r = (kgrp == 0) ? res.r[q]
                          : (kgrp == 1) ? res.r[4 + q]
                          : (kgrp == 2) ? res.r[8 + q]
                          :               res.r[12 + q];
            const float2* tl = tb2 + (kgrp * 4 + q) * T_SIZE;
            float py = cyp * r;
            float fy0 = floorf(py);
            fyA = py - fy0;
            unsigned y0 = (unsigned)(int)fy0;
            unsigned hy0 = y0 * PRIME_Y, hy1 = (y0 + 1u) * PRIME_Y;
#pragma unroll
            for (int mt = 0; mt < 4; ++mt) {
                const float cxp = ((float)(i0 + mt) + 0.5f) * (1.0f / IMG);
                float px = cxp * r;
                float fx0 = floorf(px);
                fxA[mt] = px - fx0;
                unsigned x0 = (unsigned)(int)fx0;
                fA[mt][0] = tl[(x0 ^ hy0) & (T_SIZE - 1)];
                fA[mt][1] = tl[((x0 + 1u) ^ hy0) & (T_SIZE - 1)];
                fA[mt][2] = tl[(x0 ^ hy1) & (T_SIZE - 1)];
                fA[mt][3] = tl[((x0 + 1u) ^ hy1) & (T_SIZE - 1)];
            }
        }
        {   // level q = 2h + 1
            const int q = 2 * h + 1;
            const float r = (kgrp == 0) ? res.r[q]
                          : (kgrp == 1) ? res.r[4 + q]
                          : (kgrp == 2) ? res.r[8 + q]
                          :               res.r[12 + q];
            const float2* tl = tb2 + (kgrp * 4 + q) * T_SIZE;
            float py = cyp * r;
            float fy0 = floorf(py);
            fyB = py - fy0;
            unsigned y0 = (unsigned)(int)fy0;
            unsigned hy0 = y0 * PRIME_Y, hy1 = (y0 + 1u) * PRIME_Y;
#pragma unroll
            for (int mt = 0; mt < 4; ++mt) {
                const float cxp = ((float)(i0 + mt) + 0.5f) * (1.0f / IMG);
                float px = cxp * r;
                float fx0 = floorf(px);
                fxB[mt] = px - fx0;
                unsigned x0 = (unsigned)(int)fx0;
                fB[mt][0] = tl[(x0 ^ hy0) & (T_SIZE - 1)];
                fB[mt][1] = tl[((x0 + 1u) ^ hy0) & (T_SIZE - 1)];
                fB[mt][2] = tl[(x0 ^ hy1) & (T_SIZE - 1)];
                fB[mt][3] = tl[((x0 + 1u) ^ hy1) & (T_SIZE - 1)];
            }
        }
        // consume both levels
#pragma unroll
        for (int mt = 0; mt < 4; ++mt) {
            {
                float fx = fxA[mt], fy = fyA;
                float w00 = (1.f - fx) * (1.f - fy);
                float w10 = fx * (1.f - fy);
                float w01 = (1.f - fx) * fy;
                float w11 = fx * fy;
                float e0 = fA[mt][0].x * w00 + fA[mt][1].x * w10 + fA[mt][2].x * w01 + fA[mt][3].x * w11;
                float e1 = fA[mt][0].y * w00 + fA[mt][1].y * w10 + fA[mt][2].y * w01 + fA[mt][3].y * w11;
                a1[mt][2 * (2 * h)]     = (_Float16)e0;
                a1[mt][2 * (2 * h) + 1] = (_Float16)e1;
            }
            {
                float fx = fxB[mt], fy = fyB;
                float w00 = (1.f - fx) * (1.f - fy);
                float w10 = fx * (1.f - fy);
                float w01 = (1.f - fx) * fy;
                float w11 = fx * fy;
                float e0 = fB[mt][0].x * w00 + fB[mt][1].x * w10 + fB[mt][2].x * w01 + fB[mt][3].x * w11;
                float e1 = fB[mt][0].y * w00 + fB[mt][1].y * w10 + fB[mt][2].y * w01 + fB[mt][3].y * w11;
                a1[mt][2 * (2 * h + 1)]     = (_Float16)e0;
                a1[mt][2 * (2 * h + 1) + 1] = (_Float16)e1;
            }
        }
    }

    // ---- layer 1: 32 -> 64; per-nt fused relu+write (R15-verbatim) ----
#pragma unroll
    for (int nt = 0; nt < 4; ++nt) {
        v8h bf1 = *reinterpret_cast<const v8h*>(&w1T[(nt * 16 + arow) * 32 + kgrp * 8]);
        const float bias = b1[nt * 16 + arow];
#pragma unroll
        for (int mt = 0; mt < 4; ++mt) {
            v4f c = {0.f, 0.f, 0.f, 0.f};
            c = __builtin_amdgcn_mfma_f32_16x16x32_f16(a1[mt], bf1, c, 0, 0, 0);
#pragma unroll
            for (int e = 0; e < 4; ++e)
                mbuf[wid][mt * 16 + kgrp * 4 + e][nt * 16 + arow] =
                    (_Float16)fmaxf(c[e] + bias, 0.f);
        }
    }

    // ---- layer 2: 64 -> 64; a2 fully in regs first (WAR-safe) ----
    v8h a2[4][2];
#pragma unroll
    for (int mt = 0; mt < 4; ++mt) {
        a2[mt][0] = *reinterpret_cast<const v8h*>(&mbuf[wid][mt * 16 + arow][kgrp * 8]);
        a2[mt][1] = *reinterpret_cast<const v8h*>(&mbuf[wid][mt * 16 + arow][32 + kgrp * 8]);
    }
#pragma unroll
    for (int nt = 0; nt < 4; ++nt) {
        v8h bf2a = *reinterpret_cast<const v8h*>(&w2T[(nt * 16 + arow) * 64 + kgrp * 8]);
        v8h bf2b = *reinterpret_cast<const v8h*>(&w2T[(nt * 16 + arow) * 64 + 32 + kgrp * 8]);
        const float bias = b2[nt * 16 + arow];
#pragma unroll
        for (int mt = 0; mt < 4; ++mt) {
            v4f c = {0.f, 0.f, 0.f, 0.f};
            c = __builtin_amdgcn_mfma_f32_16x16x32_f16(a2[mt][0], bf2a, c, 0, 0, 0);
            c = __builtin_amdgcn_mfma_f32_16x16x32_f16(a2[mt][1], bf2b, c, 0, 0, 0);
#pragma unroll
            for (int e = 0; e < 4; ++e)
                mbuf[wid][mt * 16 + kgrp * 4 + e][nt * 16 + arow] =
                    (_Float16)fmaxf(c[e] + bias, 0.f);
        }
    }

    // ---- layer 3: 64 -> 3 (padded 16), tanh, coalesced row stores ----
    const float bias3 = (arow < 3) ? b3[arow] : 0.f;
#pragma unroll
    for (int mt = 0; mt < 4; ++mt) {
        v8h bf3a = *reinterpret_cast<const v8h*>(&w3T[arow * 64 + kgrp * 8]);
        v8h bf3b = *reinterpret_cast<const v8h*>(&w3T[arow * 64 + 32 + kgrp * 8]);
        v8h a0  = *reinterpret_cast<const v8h*>(&mbuf[wid][mt * 16 + arow][kgrp * 8]);
        v8h a1v = *reinterpret_cast<const v8h*>(&mbuf[wid][mt * 16 + arow][32 + kgrp * 8]);
        v4f c = {0.f, 0.f, 0.f, 0.f};
        c = __builtin_amdgcn_mfma_f32_16x16x32_f16(a0,  bf3a, c, 0, 0, 0);
        c = __builtin_amdgcn_mfma_f32_16x16x32_f16(a1v, bf3b, c, 0, 0, 0);
        if (arow < 3) {
            float4 st;
            st.x = tanhf(c[0] + bias3);
            st.y = tanhf(c[1] + bias3);
            st.z = tanhf(c[2] + bias3);
            st.w = tanhf(c[3] + bias3);
            size_t idx = ((size_t)b * 3 + arow) * N_PIX
                       + (size_t)(i0 + mt) * IMG + j0 + kgrp * 4;
            *reinterpret_cast<float4*>(&out[idx]) = st;
        }
    }
}

extern "C" void kernel_launch(void* const* d_in, const int* in_sizes, int n_in,
                              void* d_out, int out_size, void* d_ws, size_t ws_size,
                              hipStream_t stream)
{
    const float* z  = (const float*)d_in[0];
    const float* wt = (const float*)d_in[1];
    const float* bt = (const float*)d_in[2];
    const float* w1 = (const float*)d_in[3];
    const float* b1 = (const float*)d_in[4];
    const float* w2 = (const float*)d_in[5];
    const float* b2 = (const float*)d_in[6];
    const float* w3 = (const float*)d_in[7];
    const float* b3 = (const float*)d_in[8];
    float* out  = (float*)d_out;

    char* ws = (char*)d_ws;
    float*     tabs = (float*)ws;                            // 4 MB
    float*     part = (float*)(ws + (4 << 20));              // 16 MB partials
    _Float16*  w1T  = (_Float16*)(ws + (20 << 20));          // 4 KB
    _Float16*  w2T  = (_Float16*)(ws + (20 << 20) + 4096);   // 8 KB
    _Float16*  w3T  = (_Float16*)(ws + (20 << 20) + 12288);  // 2 KB
    float*     zT   = (float*)(ws + (20 << 20) + 16384);     // 16 KB

    ResArr ra;
    const double growth = std::exp((std::log(256.0) - std::log(16.0)) / 15.0);
    for (int l = 0; l < TABLE_NUM; ++l)
        ra.r[l] = (float)(16.0 * std::pow(growth, (double)l));

    prep_weights<<<16, 256, 0, stream>>>(w1, w2, w3, z, w1T, w2T, w3T, zT);
    gen_partial<<<KCHUNK * (NG4 / 256), 256, 0, stream>>>(zT, wt, part);
    gen_reduce<<<BATCH * NG4 / 256, 256, 0, stream>>>(part, bt, tabs);
    hash_mlp<<<BATCH * (N_PIX / 256), 256, 0, stream>>>(
        tabs, w1T, w2T, w3T, b1, b2, b3, out, ra);
}